// Round 20
// baseline (806.723 us; speedup 1.0000x reference)
//
#include <hip/hip_runtime.h>

typedef _Float16 half8 __attribute__((ext_vector_type(8)));
typedef __fp16 fp16x2 __attribute__((ext_vector_type(2)));
typedef float floatx4 __attribute__((ext_vector_type(4)));
typedef float f4v __attribute__((ext_vector_type(4)));
typedef unsigned long long ull;

#define NSLICE 8

// ---------- helpers ----------

__device__ __forceinline__ unsigned fmap(float f) {
    unsigned u = __float_as_uint(f);
    return (u & 0x80000000u) ? ~u : (u | 0x80000000u);
}
__device__ __forceinline__ float funmap(unsigned m) {
    unsigned u = (m & 0x80000000u) ? (m & 0x7FFFFFFFu) : ~m;
    return __uint_as_float(u);
}

__device__ __forceinline__ half8 nt_load_h8(const half8* p) {
    return __builtin_nontemporal_load(p);
}
__device__ __forceinline__ f4v nt_load_f4(const f4v* p) {
    return __builtin_nontemporal_load(p);
}
__device__ __forceinline__ void nt_store_h8(half8 v, half8* p) {
    __builtin_nontemporal_store(v, p);
}
__device__ __forceinline__ void nt_store_f4(f4v v, f4v* p) {
    __builtin_nontemporal_store(v, p);
}

// Exact two-term split WITH row-scale (B / memory keys).
__device__ __forceinline__ void split8n(const f4v& v0, const f4v& v1, float rn_,
                                        half8& h, half8& l) {
    float s[8];
    #pragma unroll
    for (int j = 0; j < 4; ++j) { s[j] = v0[j] * rn_; s[4 + j] = v1[j] * rn_; }
    #pragma unroll
    for (int j = 0; j < 8; j += 2) {
        fp16x2 hh = __builtin_amdgcn_cvt_pkrtz(s[j], s[j + 1]);
        h[j] = (_Float16)hh[0]; h[j + 1] = (_Float16)hh[1];
        float r0 = (s[j]     - (float)hh[0]) * 2048.0f;
        float r1 = (s[j + 1] - (float)hh[1]) * 2048.0f;
        fp16x2 ll = __builtin_amdgcn_cvt_pkrtz(r0, r1);
        l[j] = (_Float16)ll[0]; l[j + 1] = (_Float16)ll[1];
    }
}

// Exact two-term split WITHOUT scaling (A / queries & updates). Row norm is a
// positive constant per row -> argmax/argmin invariant; applied in finish.
__device__ __forceinline__ void split8r(const f4v& v0, const f4v& v1,
                                        half8& h, half8& l) {
    #pragma unroll
    for (int j = 0; j < 4; j += 2) {
        fp16x2 hh = __builtin_amdgcn_cvt_pkrtz(v0[j], v0[j + 1]);
        h[j] = (_Float16)hh[0]; h[j + 1] = (_Float16)hh[1];
        float r0 = (v0[j]     - (float)hh[0]) * 2048.0f;
        float r1 = (v0[j + 1] - (float)hh[1]) * 2048.0f;
        fp16x2 ll = __builtin_amdgcn_cvt_pkrtz(r0, r1);
        l[j] = (_Float16)ll[0]; l[j + 1] = (_Float16)ll[1];
    }
    #pragma unroll
    for (int j = 0; j < 4; j += 2) {
        fp16x2 hh = __builtin_amdgcn_cvt_pkrtz(v1[j], v1[j + 1]);
        h[4 + j] = (_Float16)hh[0]; h[4 + j + 1] = (_Float16)hh[1];
        float r0 = (v1[j]     - (float)hh[0]) * 2048.0f;
        float r1 = (v1[j + 1] - (float)hh[1]) * 2048.0f;
        fp16x2 ll = __builtin_amdgcn_cvt_pkrtz(r0, r1);
        l[4 + j] = (_Float16)ll[0]; l[4 + j + 1] = (_Float16)ll[1];
    }
}

// ---------- small kernels ----------

__global__ void init_kernel(ull* packed, unsigned* maxsim,
                            ull* minall, ull* minsame, int Q, int Bn) {
    int i = blockIdx.x * blockDim.x + threadIdx.x;
    if (i < NSLICE * Q) packed[i] = 0ULL;
    if (i < NSLICE * Bn) { maxsim[i] = 0u; minall[i] = ~0ULL; minsame[i] = ~0ULL; }
}

// One wave per row: rn[row] = 1 / max(||X[row,:256]||, 1e-12)
__global__ void norms_kernel(const float* __restrict__ X, float* __restrict__ rn, int rows) {
    int w = (blockIdx.x * blockDim.x + threadIdx.x) >> 6;
    int lane = threadIdx.x & 63;
    if (w >= rows) return;
    float4 v = *(const float4*)&X[(long)w * 256 + lane * 4];
    float s = v.x * v.x + v.y * v.y + v.z * v.z + v.w * v.w;
    #pragma unroll
    for (int o = 32; o >= 1; o >>= 1) s += __shfl_xor(s, o, 64);
    if (lane == 0) rn[w] = 1.0f / fmaxf(sqrtf(s), 1e-12f);
}

// Normalize + split memory keys into fragment-ordered fp16 hi/lo arrays.
__global__ __launch_bounds__(256) void prep_b(const float* __restrict__ mk,
                                              _Float16* __restrict__ Bh,
                                              _Float16* __restrict__ Bl, int M) {
    __shared__ float tile[16][272];
    __shared__ float rns[16];
    const int mt = blockIdx.x;
    const int m0 = mt << 4;
    const int t = threadIdx.x;

    #pragma unroll
    for (int i = 0; i < 4; ++i) {
        int flat = i * 256 + t;          // 1024 float4 = 16 rows x 64
        int row = flat >> 6;
        int c4 = (flat & 63) << 2;
        f4v f = (f4v){0.f, 0.f, 0.f, 0.f};
        if (m0 + row < M) f = nt_load_f4((const f4v*)&mk[((long)(m0 + row)) * 256 + c4]);
        *(f4v*)&tile[row][c4] = f;
    }
    __syncthreads();

    const int wave = t >> 6, lane = t & 63;
    #pragma unroll
    for (int rr = 0; rr < 4; ++rr) {
        int row = wave * 4 + rr;
        f4v v = *(f4v*)&tile[row][lane << 2];
        float s = v.x * v.x + v.y * v.y + v.z * v.z + v.w * v.w;
        #pragma unroll
        for (int o = 32; o >= 1; o >>= 1) s += __shfl_xor(s, o, 64);
        if (lane == 0) rns[row] = 1.0f / fmaxf(sqrtf(s), 1e-12f);
    }
    __syncthreads();

    #pragma unroll
    for (int i = 0; i < 2; ++i) {
        int fi = i * 256 + t;            // 512 half8 slots: 8 kc x 64 fl
        int kc = fi >> 6;
        int fl = fi & 63;
        int r = fl & 15, sub = fl >> 4;
        int k0 = (kc << 5) + (sub << 3);
        float rn = rns[r];
        f4v v0 = *(f4v*)&tile[r][k0];
        f4v v1 = *(f4v*)&tile[r][k0 + 4];
        half8 h, l;
        split8n(v0, v1, rn, h, l);
        long idx = ((long)mt * 8 + kc) * 64 + fl;
        nt_store_h8(h, ((half8*)Bh) + idx);
        nt_store_h8(l, ((half8*)Bl) + idx);
    }
}

// ---------- fused retrieve + update GEMM ----------
// R16 geometry (best measured: 633 us) + XCD-LOCAL SLICED reduction buffers:
// slice = blockIdx & 7. Under round-robin block->XCD dispatch all
// writers/readers of a slice live on one XCD -> the filter loads and atomics
// are L2-local (no cross-XCD line migration, R16's residual ~9.6K cyc/iter
// stall). Slicing is performance-only; finish kernels merge all slices.

__global__ __launch_bounds__(512, 4) void retrieve_fused(
    const float* __restrict__ qf, const float* __restrict__ uf,
    const half8* __restrict__ Bh, const half8* __restrict__ Bl,
    const int* __restrict__ mv, const int* __restrict__ lbl,
    ull* __restrict__ packed, unsigned* __restrict__ maxsim,
    ull* __restrict__ minall, ull* __restrict__ minsame,
    int M, int Mtiles, int Q, int Bn) {
    __shared__ half8 AhL[2][512];   // [buf][kc*64 + fl]   8 KB each
    __shared__ half8 AlL[2][512];

    const int tid = threadIdx.x;
    const int wave = tid >> 6, lane = tid & 63;
    const int mset = blockIdx.x >> 1;
    const int half = blockIdx.x & 1;
    const int tmt = mset * 8 + wave;            // this wave's 16-col m-tile
    const bool valid = tmt < Mtiles;
    const int m0w = valid ? tmt * 16 + (lane & 15) : 0;

    // XCD-local slice of the reduction buffers
    const int slice = blockIdx.x & (NSLICE - 1);
    ull* pk = packed + (long)slice * Q;
    unsigned* msl = maxsim + slice * Bn;
    ull* mal = minall + slice * Bn;
    ull* msm = minsame + slice * Bn;

    // B fragments -> registers (once per kernel)
    half8 bhr[8], blr[8];
    #pragma unroll
    for (int kc = 0; kc < 8; ++kc) {
        if (valid) {
            bhr[kc] = nt_load_h8(&Bh[((long)tmt * 8 + kc) * 64 + lane]);
            blr[kc] = nt_load_h8(&Bl[((long)tmt * 8 + kc) * 64 + lane]);
        } else {
            bhr[kc] = (half8){0, 0, 0, 0, 0, 0, 0, 0};
            blr[kc] = (half8){0, 0, 0, 0, 0, 0, 0, 0};
        }
    }
    const int mvv = valid ? mv[m0w] : -2;
    const unsigned lowbits = ~(unsigned)m0w;

    const int QT = Q >> 4;            // 128 retrieve tiles
    const int NT = QT + (Bn >> 4);    // + 8 update tiles = 136

    // this block's half-range of row-tiles
    const int start = half ? (NT >> 1) : 0;
    const int end   = half ? NT : (NT >> 1);
    const int len   = end - start;

    // cooperative stage of row-tile qt into LDS buffer b
    auto stage = [&](int b, int qt) {
        int kc = tid >> 6;            // 0..7
        int fl = tid & 63;
        int row = qt * 16 + (fl & 15);
        const float* src = (row < Q) ? &qf[(long)row * 256]
                                     : &uf[(long)(row - Q) * 256];
        int k0 = (kc << 5) + ((fl >> 4) << 3);
        f4v v0 = *(const f4v*)(src + k0);
        f4v v1 = *(const f4v*)(src + k0 + 4);
        half8 h, l;
        split8r(v0, v1, h, l);
        AhL[b][kc * 64 + fl] = h;
        AlL[b][kc * 64 + fl] = l;
    };

    const int g4 = ((lane >> 4) << 2);
    int qt = start + (mset % len);    // staggered start within the half-range
    stage(0, qt);
    int buf = 0;

    #pragma unroll 1
    for (int ii = 0; ii < len; ++ii) {
        int qtn = qt + 1; if (qtn == end) qtn = start;
        __syncthreads();
        if (ii + 1 < len) stage(buf ^ 1, qtn);

        floatx4 accH  = (floatx4){0.f, 0.f, 0.f, 0.f};
        floatx4 accMa = (floatx4){0.f, 0.f, 0.f, 0.f};
        floatx4 accMb = (floatx4){0.f, 0.f, 0.f, 0.f};
        #pragma unroll
        for (int kc = 0; kc < 8; ++kc) {
            half8 ah = AhL[buf][kc * 64 + lane];
            half8 al = AlL[buf][kc * 64 + lane];
            accH  = __builtin_amdgcn_mfma_f32_16x16x32_f16(ah, bhr[kc], accH,  0, 0, 0);
            accMa = __builtin_amdgcn_mfma_f32_16x16x32_f16(ah, blr[kc], accMa, 0, 0, 0);
            accMb = __builtin_amdgcn_mfma_f32_16x16x32_f16(al, bhr[kc], accMb, 0, 0, 0);
        }
        buf ^= 1;

        if (valid) {
            if (qt < QT) {
                // ---- retrieve epilogue: per-lane monotone filter + atomic ----
                int qb = (qt << 4) + g4;
                #pragma unroll
                for (int r = 0; r < 4; ++r) {
                    float s = accH[r] + (accMa[r] + accMb[r]) * (1.0f / 2048.0f);
                    ull key = (((ull)fmap(s)) << 32) | lowbits;
                    if (key > pk[qb + r]) atomicMax(&pk[qb + r], key);
                }
            } else {
                // ---- update epilogue: per-lane filters + atomics ----
                int ub = ((qt - QT) << 4) + g4;
                #pragma unroll
                for (int r = 0; r < 4; ++r) {
                    float s = accH[r] + (accMa[r] + accMb[r]) * (1.0f / 2048.0f);
                    unsigned ms = fmap(s);
                    ull key = (((ull)ms) << 32) | (unsigned)m0w;
                    int lb = lbl[ub + r];
                    if (ms > msl[ub + r]) atomicMax(&msl[ub + r], ms);
                    if (key < mal[ub + r]) atomicMin(&mal[ub + r], key);
                    if (lb == mvv && key < msm[ub + r]) atomicMin(&msm[ub + r], key);
                }
            }
        }
        qt = qtn;
    }
}

// ---------- finish / output kernels (merge slices) ----------

__global__ void finish_retrieve(const ull* __restrict__ packed,
                                const int* __restrict__ memvals,
                                const float* __restrict__ rq,
                                float* __restrict__ out, int Q) {
    int q = blockIdx.x * blockDim.x + threadIdx.x;
    if (q >= Q) return;
    ull key = 0ULL;
    #pragma unroll
    for (int s = 0; s < NSLICE; ++s) {
        ull k = packed[(long)s * Q + q];
        if (k > key) key = k;
    }
    unsigned m = ~((unsigned)(key & 0xFFFFFFFFu));
    float conf = funmap((unsigned)(key >> 32)) * rq[q];   // apply row norm here
    out[q] = (float)memvals[m];
    out[Q + q] = conf;
}

__global__ void finish_upd(const unsigned* __restrict__ maxsim,
                           const ull* __restrict__ minall,
                           const ull* __restrict__ minsame,
                           const float* __restrict__ ru,
                           int* __restrict__ wtgt, int Bn) {
    __shared__ int tg[256];
    __shared__ unsigned char du[256];
    int b = threadIdx.x;
    int t = -1; bool d = false;
    if (b < Bn) {
        unsigned ms = 0u; ull ka = ~0ULL, ks = ~0ULL;
        #pragma unroll
        for (int s = 0; s < NSLICE; ++s) {
            unsigned m2 = maxsim[s * Bn + b];
            if (m2 > ms) ms = m2;
            ull a2 = minall[s * Bn + b];
            if (a2 < ka) ka = a2;
            ull s2 = minsame[s * Bn + b];
            if (s2 < ks) ks = s2;
        }
        d = funmap(ms) * ru[b] < 0.8f;                    // apply row norm here
        t = (ks != ~0ULL) ? (int)(ks & 0xFFFFFFFFu) : (int)(ka & 0xFFFFFFFFu);
        tg[b] = t; du[b] = d ? 1 : 0;
    }
    __syncthreads();
    if (b < Bn) {
        bool win = d;
        if (win)
            for (int b2 = b + 1; b2 < Bn; ++b2)
                if (du[b2] && tg[b2] == t) { win = false; break; }
        wtgt[b] = win ? t : -1;
    }
}

__global__ void copy_keys(const f4v* __restrict__ src, f4v* __restrict__ dst, long n4) {
    long i = blockIdx.x * (long)blockDim.x + threadIdx.x;
    long stride = (long)gridDim.x * blockDim.x;
    for (; i < n4; i += stride) nt_store_f4(nt_load_f4(&src[i]), &dst[i]);
}

__global__ void copy_vals(const int* __restrict__ src, float* __restrict__ dst, int n) {
    int i = blockIdx.x * blockDim.x + threadIdx.x;
    if (i < n) dst[i] = (float)src[i];
}

__global__ void scatter_kernel(const int* __restrict__ wtgt, const float4* __restrict__ upd4,
                               const int* __restrict__ lbl, float4* __restrict__ keys4,
                               float* __restrict__ vals) {
    int b = blockIdx.x;
    int t = wtgt[b];
    if (t < 0) return;
    int l = threadIdx.x; // 64 threads x float4 = 256 floats
    keys4[(long)t * 64 + l] = upd4[(long)b * 64 + l];
    if (l == 0) vals[t] = (float)lbl[b];
}

// ---------- launch ----------

extern "C" void kernel_launch(void* const* d_in, const int* in_sizes, int n_in,
                              void* d_out, int out_size, void* d_ws, size_t ws_size,
                              hipStream_t stream) {
    const float* qf = (const float*)d_in[0];
    const float* mk = (const float*)d_in[1];
    const int*   mv = (const int*)d_in[2];
    const float* uf = (const float*)d_in[3];
    const int*   ul = (const int*)d_in[4];

    const int D = 256;
    const int Q = in_sizes[0] / D;   // 2048
    const int M = in_sizes[2];       // 100000
    const int Bn = in_sizes[3] / D;  // 128

    float* out = (float*)d_out;
    float* out_keys = out + 2 * (long)Q;
    float* out_vals = out_keys + (long)M * D;

    // B fragment arrays live in the out_keys region (exact fit). copy_keys
    // overwrites them afterwards.
    _Float16* Bh = (_Float16*)out_keys;
    _Float16* Bl = Bh + (size_t)M * D;

    // Sliced reduction scratch + norms live in the out_vals region (400 KB;
    // we use ~170 KB). d_out is cacheable VRAM unlike d_ws (L2-bypassed).
    // copy_vals overwrites it at the end (stream-ordered).
    char* ov = (char*)out_vals;
    ull* packed      = (ull*)(ov);                          // 8*2048*8 = 128 KB
    ull* minall      = (ull*)(ov + 131072);                 // 8*128*8 = 8 KB
    ull* minsame     = (ull*)(ov + 139264);                 // 8 KB
    unsigned* maxsim = (unsigned*)(ov + 147456);            // 4 KB
    float* rq        = (float*)(ov + 151552);               // 8 KB
    float* ru        = (float*)(ov + 159744);               // 0.5 KB

    // d_ws only holds atomic-free, rarely-touched data.
    int* wtgt = (int*)d_ws;

    const int Mtiles = (M + 15) / 16;          // 6250
    const int msets = (Mtiles + 7) / 8;        // 782
    const int grid_g = msets * 2;              // 1564 (half q-sweep each)

    int initN = NSLICE * (Q > Bn ? Q : Bn);
    init_kernel<<<(initN + 255) / 256, 256, 0, stream>>>(packed, maxsim, minall, minsame, Q, Bn);

    norms_kernel<<<(Q + 3) / 4, 256, 0, stream>>>(qf, rq, Q);
    norms_kernel<<<(Bn + 3) / 4, 256, 0, stream>>>(uf, ru, Bn);

    prep_b<<<Mtiles, 256, 0, stream>>>(mk, Bh, Bl, M);

    retrieve_fused<<<grid_g, 512, 0, stream>>>(
        qf, uf, (const half8*)Bh, (const half8*)Bl, mv, ul,
        packed, maxsim, minall, minsame, M, Mtiles, Q, Bn);

    finish_retrieve<<<(Q + 255) / 256, 256, 0, stream>>>(packed, mv, rq, out, Q);
    finish_upd<<<1, Bn, 0, stream>>>(maxsim, minall, minsame, ru, wtgt, Bn);

    // Overwrite scratch regions with the real outputs (stream-ordered).
    copy_keys<<<2048, 256, 0, stream>>>((const f4v*)mk, (f4v*)out_keys, (long)M * (D / 4));
    copy_vals<<<(M + 255) / 256, 256, 0, stream>>>(mv, out_vals, M);
    scatter_kernel<<<Bn, 64, 0, stream>>>(wtgt, (const float4*)uf, ul, (float4*)out_keys, out_vals);
}

// Round 21
// 662.605 us; speedup vs baseline: 1.2175x; 1.2175x over previous
//
#include <hip/hip_runtime.h>

typedef _Float16 half8 __attribute__((ext_vector_type(8)));
typedef __fp16 fp16x2 __attribute__((ext_vector_type(2)));
typedef float floatx4 __attribute__((ext_vector_type(4)));
typedef float f4v __attribute__((ext_vector_type(4)));
typedef unsigned long long ull;

// ---------- helpers ----------

__device__ __forceinline__ unsigned fmap(float f) {
    unsigned u = __float_as_uint(f);
    return (u & 0x80000000u) ? ~u : (u | 0x80000000u);
}
__device__ __forceinline__ float funmap(unsigned m) {
    unsigned u = (m & 0x80000000u) ? (m & 0x7FFFFFFFu) : ~m;
    return __uint_as_float(u);
}

__device__ __forceinline__ half8 nt_load_h8(const half8* p) {
    return __builtin_nontemporal_load(p);
}
__device__ __forceinline__ f4v nt_load_f4(const f4v* p) {
    return __builtin_nontemporal_load(p);
}
__device__ __forceinline__ void nt_store_h8(half8 v, half8* p) {
    __builtin_nontemporal_store(v, p);
}
__device__ __forceinline__ void nt_store_f4(f4v v, f4v* p) {
    __builtin_nontemporal_store(v, p);
}

// Exact two-term split WITH row-scale (B / memory keys).
__device__ __forceinline__ void split8n(const f4v& v0, const f4v& v1, float rn_,
                                        half8& h, half8& l) {
    float s[8];
    #pragma unroll
    for (int j = 0; j < 4; ++j) { s[j] = v0[j] * rn_; s[4 + j] = v1[j] * rn_; }
    #pragma unroll
    for (int j = 0; j < 8; j += 2) {
        fp16x2 hh = __builtin_amdgcn_cvt_pkrtz(s[j], s[j + 1]);
        h[j] = (_Float16)hh[0]; h[j + 1] = (_Float16)hh[1];
        float r0 = (s[j]     - (float)hh[0]) * 2048.0f;
        float r1 = (s[j + 1] - (float)hh[1]) * 2048.0f;
        fp16x2 ll = __builtin_amdgcn_cvt_pkrtz(r0, r1);
        l[j] = (_Float16)ll[0]; l[j + 1] = (_Float16)ll[1];
    }
}

// Exact two-term split WITHOUT scaling (A / queries & updates). Row norm is a
// positive constant per row -> argmax/argmin invariant; applied in finish.
__device__ __forceinline__ void split8r(const f4v& v0, const f4v& v1,
                                        half8& h, half8& l) {
    #pragma unroll
    for (int j = 0; j < 4; j += 2) {
        fp16x2 hh = __builtin_amdgcn_cvt_pkrtz(v0[j], v0[j + 1]);
        h[j] = (_Float16)hh[0]; h[j + 1] = (_Float16)hh[1];
        float r0 = (v0[j]     - (float)hh[0]) * 2048.0f;
        float r1 = (v0[j + 1] - (float)hh[1]) * 2048.0f;
        fp16x2 ll = __builtin_amdgcn_cvt_pkrtz(r0, r1);
        l[j] = (_Float16)ll[0]; l[j + 1] = (_Float16)ll[1];
    }
    #pragma unroll
    for (int j = 0; j < 4; j += 2) {
        fp16x2 hh = __builtin_amdgcn_cvt_pkrtz(v1[j], v1[j + 1]);
        h[4 + j] = (_Float16)hh[0]; h[4 + j + 1] = (_Float16)hh[1];
        float r0 = (v1[j]     - (float)hh[0]) * 2048.0f;
        float r1 = (v1[j + 1] - (float)hh[1]) * 2048.0f;
        fp16x2 ll = __builtin_amdgcn_cvt_pkrtz(r0, r1);
        l[4 + j] = (_Float16)ll[0]; l[4 + j + 1] = (_Float16)ll[1];
    }
}

// ---------- small kernels ----------

__global__ void init_kernel(ull* packed, unsigned* maxsim,
                            ull* minall, ull* minsame, int Q, int Bn) {
    int i = blockIdx.x * blockDim.x + threadIdx.x;
    if (i < Q) packed[i] = 0ULL;
    if (i < Bn) { maxsim[i] = 0u; minall[i] = ~0ULL; minsame[i] = ~0ULL; }
}

// One wave per row: rn[row] = 1 / max(||X[row,:256]||, 1e-12)
__global__ void norms_kernel(const float* __restrict__ X, float* __restrict__ rn, int rows) {
    int w = (blockIdx.x * blockDim.x + threadIdx.x) >> 6;
    int lane = threadIdx.x & 63;
    if (w >= rows) return;
    float4 v = *(const float4*)&X[(long)w * 256 + lane * 4];
    float s = v.x * v.x + v.y * v.y + v.z * v.z + v.w * v.w;
    #pragma unroll
    for (int o = 32; o >= 1; o >>= 1) s += __shfl_xor(s, o, 64);
    if (lane == 0) rn[w] = 1.0f / fmaxf(sqrtf(s), 1e-12f);
}

// Normalize + split memory keys into fragment-ordered fp16 hi/lo arrays.
__global__ __launch_bounds__(256) void prep_b(const float* __restrict__ mk,
                                              _Float16* __restrict__ Bh,
                                              _Float16* __restrict__ Bl, int M) {
    __shared__ float tile[16][272];
    __shared__ float rns[16];
    const int mt = blockIdx.x;
    const int m0 = mt << 4;
    const int t = threadIdx.x;

    #pragma unroll
    for (int i = 0; i < 4; ++i) {
        int flat = i * 256 + t;          // 1024 float4 = 16 rows x 64
        int row = flat >> 6;
        int c4 = (flat & 63) << 2;
        f4v f = (f4v){0.f, 0.f, 0.f, 0.f};
        if (m0 + row < M) f = nt_load_f4((const f4v*)&mk[((long)(m0 + row)) * 256 + c4]);
        *(f4v*)&tile[row][c4] = f;
    }
    __syncthreads();

    const int wave = t >> 6, lane = t & 63;
    #pragma unroll
    for (int rr = 0; rr < 4; ++rr) {
        int row = wave * 4 + rr;
        f4v v = *(f4v*)&tile[row][lane << 2];
        float s = v.x * v.x + v.y * v.y + v.z * v.z + v.w * v.w;
        #pragma unroll
        for (int o = 32; o >= 1; o >>= 1) s += __shfl_xor(s, o, 64);
        if (lane == 0) rns[row] = 1.0f / fmaxf(sqrtf(s), 1e-12f);
    }
    __syncthreads();

    #pragma unroll
    for (int i = 0; i < 2; ++i) {
        int fi = i * 256 + t;            // 512 half8 slots: 8 kc x 64 fl
        int kc = fi >> 6;
        int fl = fi & 63;
        int r = fl & 15, sub = fl >> 4;
        int k0 = (kc << 5) + (sub << 3);
        float rn = rns[r];
        f4v v0 = *(f4v*)&tile[r][k0];
        f4v v1 = *(f4v*)&tile[r][k0 + 4];
        half8 h, l;
        split8n(v0, v1, rn, h, l);
        long idx = ((long)mt * 8 + kc) * 64 + fl;
        nt_store_h8(h, ((half8*)Bh) + idx);
        nt_store_h8(l, ((half8*)Bl) + idx);
    }
}

// ---------- fused retrieve + update GEMM (B-in-registers, split q-sweep) ----------
// Best measured configuration (R16: 633 us). Two blocks per m-tile-set sweep
// half of the 136 row-tiles each (grid 1564 -> clean round quantization).
// Per wave: one 16-col m-tile, B hi/lo fragments in 64 regs for the kernel's
// lifetime; A row-tiles staged to double-buffered LDS cooperatively;
// per-lane monotone filter + atomic epilogue (stagger keeps words warm).
// Neighboring configs all measured worse: 2 tiles/wave (R17), shuffle reduce
// (R13), DPP+fire-and-forget (R19), XCD-sliced buffers (R20).

__global__ __launch_bounds__(512, 4) void retrieve_fused(
    const float* __restrict__ qf, const float* __restrict__ uf,
    const half8* __restrict__ Bh, const half8* __restrict__ Bl,
    const int* __restrict__ mv, const int* __restrict__ lbl,
    ull* __restrict__ packed, unsigned* __restrict__ maxsim,
    ull* __restrict__ minall, ull* __restrict__ minsame,
    int M, int Mtiles, int Q, int Bn) {
    __shared__ half8 AhL[2][512];   // [buf][kc*64 + fl]   8 KB each
    __shared__ half8 AlL[2][512];

    const int tid = threadIdx.x;
    const int wave = tid >> 6, lane = tid & 63;
    const int mset = blockIdx.x >> 1;
    const int half = blockIdx.x & 1;
    const int tmt = mset * 8 + wave;            // this wave's 16-col m-tile
    const bool valid = tmt < Mtiles;
    const int m0w = valid ? tmt * 16 + (lane & 15) : 0;

    // B fragments -> registers (once per kernel)
    half8 bhr[8], blr[8];
    #pragma unroll
    for (int kc = 0; kc < 8; ++kc) {
        if (valid) {
            bhr[kc] = nt_load_h8(&Bh[((long)tmt * 8 + kc) * 64 + lane]);
            blr[kc] = nt_load_h8(&Bl[((long)tmt * 8 + kc) * 64 + lane]);
        } else {
            bhr[kc] = (half8){0, 0, 0, 0, 0, 0, 0, 0};
            blr[kc] = (half8){0, 0, 0, 0, 0, 0, 0, 0};
        }
    }
    const int mvv = valid ? mv[m0w] : -2;
    const unsigned lowbits = ~(unsigned)m0w;

    const int QT = Q >> 4;            // 128 retrieve tiles
    const int NT = QT + (Bn >> 4);    // + 8 update tiles = 136

    // this block's half-range of row-tiles
    const int start = half ? (NT >> 1) : 0;
    const int end   = half ? NT : (NT >> 1);
    const int len   = end - start;

    // cooperative stage of row-tile qt into LDS buffer b
    auto stage = [&](int b, int qt) {
        int kc = tid >> 6;            // 0..7
        int fl = tid & 63;
        int row = qt * 16 + (fl & 15);
        const float* src = (row < Q) ? &qf[(long)row * 256]
                                     : &uf[(long)(row - Q) * 256];
        int k0 = (kc << 5) + ((fl >> 4) << 3);
        f4v v0 = *(const f4v*)(src + k0);
        f4v v1 = *(const f4v*)(src + k0 + 4);
        half8 h, l;
        split8r(v0, v1, h, l);
        AhL[b][kc * 64 + fl] = h;
        AlL[b][kc * 64 + fl] = l;
    };

    const int g4 = ((lane >> 4) << 2);
    int qt = start + (mset % len);    // staggered start within the half-range
    stage(0, qt);
    int buf = 0;

    #pragma unroll 1
    for (int ii = 0; ii < len; ++ii) {
        int qtn = qt + 1; if (qtn == end) qtn = start;
        __syncthreads();
        if (ii + 1 < len) stage(buf ^ 1, qtn);

        floatx4 accH  = (floatx4){0.f, 0.f, 0.f, 0.f};
        floatx4 accMa = (floatx4){0.f, 0.f, 0.f, 0.f};
        floatx4 accMb = (floatx4){0.f, 0.f, 0.f, 0.f};
        #pragma unroll
        for (int kc = 0; kc < 8; ++kc) {
            half8 ah = AhL[buf][kc * 64 + lane];
            half8 al = AlL[buf][kc * 64 + lane];
            accH  = __builtin_amdgcn_mfma_f32_16x16x32_f16(ah, bhr[kc], accH,  0, 0, 0);
            accMa = __builtin_amdgcn_mfma_f32_16x16x32_f16(ah, blr[kc], accMa, 0, 0, 0);
            accMb = __builtin_amdgcn_mfma_f32_16x16x32_f16(al, bhr[kc], accMb, 0, 0, 0);
        }
        buf ^= 1;

        if (valid) {
            if (qt < QT) {
                // ---- retrieve epilogue: per-lane monotone filter + atomic ----
                int qb = (qt << 4) + g4;
                #pragma unroll
                for (int r = 0; r < 4; ++r) {
                    float s = accH[r] + (accMa[r] + accMb[r]) * (1.0f / 2048.0f);
                    ull key = (((ull)fmap(s)) << 32) | lowbits;
                    if (key > packed[qb + r]) atomicMax(&packed[qb + r], key);
                }
            } else {
                // ---- update epilogue: per-lane filters + atomics ----
                int ub = ((qt - QT) << 4) + g4;
                #pragma unroll
                for (int r = 0; r < 4; ++r) {
                    float s = accH[r] + (accMa[r] + accMb[r]) * (1.0f / 2048.0f);
                    unsigned ms = fmap(s);
                    ull key = (((ull)ms) << 32) | (unsigned)m0w;
                    int lb = lbl[ub + r];
                    if (ms > maxsim[ub + r]) atomicMax(&maxsim[ub + r], ms);
                    if (key < minall[ub + r]) atomicMin(&minall[ub + r], key);
                    if (lb == mvv && key < minsame[ub + r]) atomicMin(&minsame[ub + r], key);
                }
            }
        }
        qt = qtn;
    }
}

// ---------- finish / output kernels ----------

__global__ void finish_retrieve(const ull* __restrict__ packed,
                                const int* __restrict__ memvals,
                                const float* __restrict__ rq,
                                float* __restrict__ out, int Q) {
    int q = blockIdx.x * blockDim.x + threadIdx.x;
    if (q >= Q) return;
    ull key = packed[q];
    unsigned m = ~((unsigned)(key & 0xFFFFFFFFu));
    float conf = funmap((unsigned)(key >> 32)) * rq[q];   // apply row norm here
    out[q] = (float)memvals[m];
    out[Q + q] = conf;
}

__global__ void finish_upd(const unsigned* __restrict__ maxsim,
                           const ull* __restrict__ minall,
                           const ull* __restrict__ minsame,
                           const float* __restrict__ ru,
                           int* __restrict__ wtgt, int Bn) {
    __shared__ int tg[256];
    __shared__ unsigned char du[256];
    int b = threadIdx.x;
    int t = -1; bool d = false;
    if (b < Bn) {
        d = funmap(maxsim[b]) * ru[b] < 0.8f;             // apply row norm here
        ull ks = minsame[b];
        ull ka = minall[b];
        t = (ks != ~0ULL) ? (int)(ks & 0xFFFFFFFFu) : (int)(ka & 0xFFFFFFFFu);
        tg[b] = t; du[b] = d ? 1 : 0;
    }
    __syncthreads();
    if (b < Bn) {
        bool win = d;
        if (win)
            for (int b2 = b + 1; b2 < Bn; ++b2)
                if (du[b2] && tg[b2] == t) { win = false; break; }
        wtgt[b] = win ? t : -1;
    }
}

__global__ void copy_keys(const f4v* __restrict__ src, f4v* __restrict__ dst, long n4) {
    long i = blockIdx.x * (long)blockDim.x + threadIdx.x;
    long stride = (long)gridDim.x * blockDim.x;
    for (; i < n4; i += stride) nt_store_f4(nt_load_f4(&src[i]), &dst[i]);
}

__global__ void copy_vals(const int* __restrict__ src, float* __restrict__ dst, int n) {
    int i = blockIdx.x * blockDim.x + threadIdx.x;
    if (i < n) dst[i] = (float)src[i];
}

__global__ void scatter_kernel(const int* __restrict__ wtgt, const float4* __restrict__ upd4,
                               const int* __restrict__ lbl, float4* __restrict__ keys4,
                               float* __restrict__ vals) {
    int b = blockIdx.x;
    int t = wtgt[b];
    if (t < 0) return;
    int l = threadIdx.x; // 64 threads x float4 = 256 floats
    keys4[(long)t * 64 + l] = upd4[(long)b * 64 + l];
    if (l == 0) vals[t] = (float)lbl[b];
}

// ---------- launch ----------

extern "C" void kernel_launch(void* const* d_in, const int* in_sizes, int n_in,
                              void* d_out, int out_size, void* d_ws, size_t ws_size,
                              hipStream_t stream) {
    const float* qf = (const float*)d_in[0];
    const float* mk = (const float*)d_in[1];
    const int*   mv = (const int*)d_in[2];
    const float* uf = (const float*)d_in[3];
    const int*   ul = (const int*)d_in[4];

    const int D = 256;
    const int Q = in_sizes[0] / D;   // 2048
    const int M = in_sizes[2];       // 100000
    const int Bn = in_sizes[3] / D;  // 128

    float* out = (float*)d_out;
    float* out_keys = out + 2 * (long)Q;
    float* out_vals = out_keys + (long)M * D;

    // B fragment arrays live in the out_keys region (exact fit). copy_keys
    // overwrites them afterwards.
    _Float16* Bh = (_Float16*)out_keys;
    _Float16* Bl = Bh + (size_t)M * D;

    // Reduction scratch + norms live in the out_vals region (cacheable d_out,
    // unlike d_ws whose reads bypass L2). copy_vals overwrites at the end.
    char* ov = (char*)out_vals;
    ull* packed      = (ull*)(ov);                         // 16 KB
    ull* minall      = (ull*)(ov + 16384);                 // 1 KB
    ull* minsame     = (ull*)(ov + 17408);                 // 1 KB
    unsigned* maxsim = (unsigned*)(ov + 18432);            // 0.5 KB
    float* rq        = (float*)(ov + 18944);               // 8 KB
    float* ru        = (float*)(ov + 27136);               // 0.5 KB

    // d_ws only holds atomic-free, rarely-touched data.
    int* wtgt = (int*)d_ws;

    const int Mtiles = (M + 15) / 16;          // 6250
    const int msets = (Mtiles + 7) / 8;        // 782
    const int grid_g = msets * 2;              // 1564 (half q-sweep each)

    int initN = (Q > Bn ? Q : Bn);
    init_kernel<<<(initN + 255) / 256, 256, 0, stream>>>(packed, maxsim, minall, minsame, Q, Bn);

    norms_kernel<<<(Q + 3) / 4, 256, 0, stream>>>(qf, rq, Q);
    norms_kernel<<<(Bn + 3) / 4, 256, 0, stream>>>(uf, ru, Bn);

    prep_b<<<Mtiles, 256, 0, stream>>>(mk, Bh, Bl, M);

    retrieve_fused<<<grid_g, 512, 0, stream>>>(
        qf, uf, (const half8*)Bh, (const half8*)Bl, mv, ul,
        packed, maxsim, minall, minsame, M, Mtiles, Q, Bn);

    finish_retrieve<<<(Q + 255) / 256, 256, 0, stream>>>(packed, mv, rq, out, Q);
    finish_upd<<<1, Bn, 0, stream>>>(maxsim, minall, minsame, ru, wtgt, Bn);

    // Overwrite scratch regions with the real outputs (stream-ordered).
    copy_keys<<<2048, 256, 0, stream>>>((const f4v*)mk, (f4v*)out_keys, (long)M * (D / 4));
    copy_vals<<<(M + 255) / 256, 256, 0, stream>>>(mv, out_vals, M);
    scatter_kernel<<<Bn, 64, 0, stream>>>(wtgt, (const float4*)uf, ul, (float4*)out_keys, out_vals);
}

// Round 22
// 616.501 us; speedup vs baseline: 1.3086x; 1.0748x over previous
//
#include <hip/hip_runtime.h>

typedef _Float16 half8 __attribute__((ext_vector_type(8)));
typedef __fp16 fp16x2 __attribute__((ext_vector_type(2)));
typedef float floatx4 __attribute__((ext_vector_type(4)));
typedef float f4v __attribute__((ext_vector_type(4)));
typedef unsigned long long ull;

// ---------- helpers ----------

__device__ __forceinline__ unsigned fmap(float f) {
    unsigned u = __float_as_uint(f);
    return (u & 0x80000000u) ? ~u : (u | 0x80000000u);
}
__device__ __forceinline__ float funmap(unsigned m) {
    unsigned u = (m & 0x80000000u) ? (m & 0x7FFFFFFFu) : ~m;
    return __uint_as_float(u);
}

__device__ __forceinline__ half8 nt_load_h8(const half8* p) {
    return __builtin_nontemporal_load(p);
}
__device__ __forceinline__ f4v nt_load_f4(const f4v* p) {
    return __builtin_nontemporal_load(p);
}
__device__ __forceinline__ void nt_store_h8(half8 v, half8* p) {
    __builtin_nontemporal_store(v, p);
}
__device__ __forceinline__ void nt_store_f4(f4v v, f4v* p) {
    __builtin_nontemporal_store(v, p);
}

// Exact two-term split WITH row-scale (B / memory keys).
__device__ __forceinline__ void split8n(const f4v& v0, const f4v& v1, float rn_,
                                        half8& h, half8& l) {
    float s[8];
    #pragma unroll
    for (int j = 0; j < 4; ++j) { s[j] = v0[j] * rn_; s[4 + j] = v1[j] * rn_; }
    #pragma unroll
    for (int j = 0; j < 8; j += 2) {
        fp16x2 hh = __builtin_amdgcn_cvt_pkrtz(s[j], s[j + 1]);
        h[j] = (_Float16)hh[0]; h[j + 1] = (_Float16)hh[1];
        float r0 = (s[j]     - (float)hh[0]) * 2048.0f;
        float r1 = (s[j + 1] - (float)hh[1]) * 2048.0f;
        fp16x2 ll = __builtin_amdgcn_cvt_pkrtz(r0, r1);
        l[j] = (_Float16)ll[0]; l[j + 1] = (_Float16)ll[1];
    }
}

// Exact two-term split WITHOUT scaling (A / queries & updates). Row norm is a
// positive constant per row -> argmax/argmin invariant; applied in finish.
__device__ __forceinline__ void split8r(const f4v& v0, const f4v& v1,
                                        half8& h, half8& l) {
    #pragma unroll
    for (int j = 0; j < 4; j += 2) {
        fp16x2 hh = __builtin_amdgcn_cvt_pkrtz(v0[j], v0[j + 1]);
        h[j] = (_Float16)hh[0]; h[j + 1] = (_Float16)hh[1];
        float r0 = (v0[j]     - (float)hh[0]) * 2048.0f;
        float r1 = (v0[j + 1] - (float)hh[1]) * 2048.0f;
        fp16x2 ll = __builtin_amdgcn_cvt_pkrtz(r0, r1);
        l[j] = (_Float16)ll[0]; l[j + 1] = (_Float16)ll[1];
    }
    #pragma unroll
    for (int j = 0; j < 4; j += 2) {
        fp16x2 hh = __builtin_amdgcn_cvt_pkrtz(v1[j], v1[j + 1]);
        h[4 + j] = (_Float16)hh[0]; h[4 + j + 1] = (_Float16)hh[1];
        float r0 = (v1[j]     - (float)hh[0]) * 2048.0f;
        float r1 = (v1[j + 1] - (float)hh[1]) * 2048.0f;
        fp16x2 ll = __builtin_amdgcn_cvt_pkrtz(r0, r1);
        l[4 + j] = (_Float16)ll[0]; l[4 + j + 1] = (_Float16)ll[1];
    }
}

// ---------- small kernels ----------

__global__ void init_kernel(ull* packed, unsigned* maxsim,
                            ull* minall, ull* minsame, int Q, int Bn) {
    int i = blockIdx.x * blockDim.x + threadIdx.x;
    if (i < Q) packed[i] = 0ULL;
    if (i < Bn) { maxsim[i] = 0u; minall[i] = ~0ULL; minsame[i] = ~0ULL; }
}

// One wave per row: rn[row] = 1 / max(||X[row,:256]||, 1e-12)
__global__ void norms_kernel(const float* __restrict__ X, float* __restrict__ rn, int rows) {
    int w = (blockIdx.x * blockDim.x + threadIdx.x) >> 6;
    int lane = threadIdx.x & 63;
    if (w >= rows) return;
    float4 v = *(const float4*)&X[(long)w * 256 + lane * 4];
    float s = v.x * v.x + v.y * v.y + v.z * v.z + v.w * v.w;
    #pragma unroll
    for (int o = 32; o >= 1; o >>= 1) s += __shfl_xor(s, o, 64);
    if (lane == 0) rn[w] = 1.0f / fmaxf(sqrtf(s), 1e-12f);
}

// Normalize + split memory keys into fragment-ordered fp16 hi/lo arrays.
__global__ __launch_bounds__(256) void prep_b(const float* __restrict__ mk,
                                              _Float16* __restrict__ Bh,
                                              _Float16* __restrict__ Bl, int M) {
    __shared__ float tile[16][272];
    __shared__ float rns[16];
    const int mt = blockIdx.x;
    const int m0 = mt << 4;
    const int t = threadIdx.x;

    #pragma unroll
    for (int i = 0; i < 4; ++i) {
        int flat = i * 256 + t;          // 1024 float4 = 16 rows x 64
        int row = flat >> 6;
        int c4 = (flat & 63) << 2;
        f4v f = (f4v){0.f, 0.f, 0.f, 0.f};
        if (m0 + row < M) f = nt_load_f4((const f4v*)&mk[((long)(m0 + row)) * 256 + c4]);
        *(f4v*)&tile[row][c4] = f;
    }
    __syncthreads();

    const int wave = t >> 6, lane = t & 63;
    #pragma unroll
    for (int rr = 0; rr < 4; ++rr) {
        int row = wave * 4 + rr;
        f4v v = *(f4v*)&tile[row][lane << 2];
        float s = v.x * v.x + v.y * v.y + v.z * v.z + v.w * v.w;
        #pragma unroll
        for (int o = 32; o >= 1; o >>= 1) s += __shfl_xor(s, o, 64);
        if (lane == 0) rns[row] = 1.0f / fmaxf(sqrtf(s), 1e-12f);
    }
    __syncthreads();

    #pragma unroll
    for (int i = 0; i < 2; ++i) {
        int fi = i * 256 + t;            // 512 half8 slots: 8 kc x 64 fl
        int kc = fi >> 6;
        int fl = fi & 63;
        int r = fl & 15, sub = fl >> 4;
        int k0 = (kc << 5) + (sub << 3);
        float rn = rns[r];
        f4v v0 = *(f4v*)&tile[r][k0];
        f4v v1 = *(f4v*)&tile[r][k0 + 4];
        half8 h, l;
        split8n(v0, v1, rn, h, l);
        long idx = ((long)mt * 8 + kc) * 64 + fl;
        nt_store_h8(h, ((half8*)Bh) + idx);
        nt_store_h8(l, ((half8*)Bl) + idx);
    }
}

// ---------- fused retrieve + update GEMM (B-in-registers, split q-sweep) ----------
// R16 structure (best measured: 633 us) + HOISTED FILTER LOADS: the 4
// packed[] filter words for the current q-tile are loaded right after the
// stage() issue, ~1900 cyc of LDS+MFMA work before their use in the epilogue
// -- hiding the cross-XCD coherence-miss latency that was fully exposed when
// loaded at the epilogue. Staleness is safe (monotone filter).

__global__ __launch_bounds__(512, 4) void retrieve_fused(
    const float* __restrict__ qf, const float* __restrict__ uf,
    const half8* __restrict__ Bh, const half8* __restrict__ Bl,
    const int* __restrict__ mv, const int* __restrict__ lbl,
    ull* __restrict__ packed, unsigned* __restrict__ maxsim,
    ull* __restrict__ minall, ull* __restrict__ minsame,
    int M, int Mtiles, int Q, int Bn) {
    __shared__ half8 AhL[2][512];   // [buf][kc*64 + fl]   8 KB each
    __shared__ half8 AlL[2][512];

    const int tid = threadIdx.x;
    const int wave = tid >> 6, lane = tid & 63;
    const int mset = blockIdx.x >> 1;
    const int half = blockIdx.x & 1;
    const int tmt = mset * 8 + wave;            // this wave's 16-col m-tile
    const bool valid = tmt < Mtiles;
    const int m0w = valid ? tmt * 16 + (lane & 15) : 0;

    // B fragments -> registers (once per kernel)
    half8 bhr[8], blr[8];
    #pragma unroll
    for (int kc = 0; kc < 8; ++kc) {
        if (valid) {
            bhr[kc] = nt_load_h8(&Bh[((long)tmt * 8 + kc) * 64 + lane]);
            blr[kc] = nt_load_h8(&Bl[((long)tmt * 8 + kc) * 64 + lane]);
        } else {
            bhr[kc] = (half8){0, 0, 0, 0, 0, 0, 0, 0};
            blr[kc] = (half8){0, 0, 0, 0, 0, 0, 0, 0};
        }
    }
    const int mvv = valid ? mv[m0w] : -2;
    const unsigned lowbits = ~(unsigned)m0w;

    const int QT = Q >> 4;            // 128 retrieve tiles
    const int NT = QT + (Bn >> 4);    // + 8 update tiles = 136

    // this block's half-range of row-tiles
    const int start = half ? (NT >> 1) : 0;
    const int end   = half ? NT : (NT >> 1);
    const int len   = end - start;

    // cooperative stage of row-tile qt into LDS buffer b
    auto stage = [&](int b, int qt) {
        int kc = tid >> 6;            // 0..7
        int fl = tid & 63;
        int row = qt * 16 + (fl & 15);
        const float* src = (row < Q) ? &qf[(long)row * 256]
                                     : &uf[(long)(row - Q) * 256];
        int k0 = (kc << 5) + ((fl >> 4) << 3);
        f4v v0 = *(const f4v*)(src + k0);
        f4v v1 = *(const f4v*)(src + k0 + 4);
        half8 h, l;
        split8r(v0, v1, h, l);
        AhL[b][kc * 64 + fl] = h;
        AlL[b][kc * 64 + fl] = l;
    };

    const int g4 = ((lane >> 4) << 2);
    int qt = start + (mset % len);    // staggered start within the half-range
    stage(0, qt);
    int buf = 0;

    #pragma unroll 1
    for (int ii = 0; ii < len; ++ii) {
        int qtn = qt + 1; if (qtn == end) qtn = start;
        __syncthreads();
        if (ii + 1 < len) stage(buf ^ 1, qtn);

        // Hoisted filter loads: issued here, consumed after the MFMA loop.
        // (Retrieve tiles only; the 8 update tiles keep in-epilogue loads.)
        const int qb = (qt << 4) + g4;
        ull pf0 = 0, pf1 = 0, pf2 = 0, pf3 = 0;
        if (valid && qt < QT) {
            pf0 = packed[qb + 0];
            pf1 = packed[qb + 1];
            pf2 = packed[qb + 2];
            pf3 = packed[qb + 3];
        }

        floatx4 accH  = (floatx4){0.f, 0.f, 0.f, 0.f};
        floatx4 accMa = (floatx4){0.f, 0.f, 0.f, 0.f};
        floatx4 accMb = (floatx4){0.f, 0.f, 0.f, 0.f};
        #pragma unroll
        for (int kc = 0; kc < 8; ++kc) {
            half8 ah = AhL[buf][kc * 64 + lane];
            half8 al = AlL[buf][kc * 64 + lane];
            accH  = __builtin_amdgcn_mfma_f32_16x16x32_f16(ah, bhr[kc], accH,  0, 0, 0);
            accMa = __builtin_amdgcn_mfma_f32_16x16x32_f16(ah, blr[kc], accMa, 0, 0, 0);
            accMb = __builtin_amdgcn_mfma_f32_16x16x32_f16(al, bhr[kc], accMb, 0, 0, 0);
        }
        buf ^= 1;

        if (valid) {
            if (qt < QT) {
                // ---- retrieve epilogue: prefetched monotone filter + atomic ----
                ull pf[4] = {pf0, pf1, pf2, pf3};
                #pragma unroll
                for (int r = 0; r < 4; ++r) {
                    float s = accH[r] + (accMa[r] + accMb[r]) * (1.0f / 2048.0f);
                    ull key = (((ull)fmap(s)) << 32) | lowbits;
                    if (key > pf[r]) atomicMax(&packed[qb + r], key);
                }
            } else {
                // ---- update epilogue: per-lane filters + atomics ----
                int ub = ((qt - QT) << 4) + g4;
                #pragma unroll
                for (int r = 0; r < 4; ++r) {
                    float s = accH[r] + (accMa[r] + accMb[r]) * (1.0f / 2048.0f);
                    unsigned ms = fmap(s);
                    ull key = (((ull)ms) << 32) | (unsigned)m0w;
                    int lb = lbl[ub + r];
                    if (ms > maxsim[ub + r]) atomicMax(&maxsim[ub + r], ms);
                    if (key < minall[ub + r]) atomicMin(&minall[ub + r], key);
                    if (lb == mvv && key < minsame[ub + r]) atomicMin(&minsame[ub + r], key);
                }
            }
        }
        qt = qtn;
    }
}

// ---------- finish / output kernels ----------

__global__ void finish_retrieve(const ull* __restrict__ packed,
                                const int* __restrict__ memvals,
                                const float* __restrict__ rq,
                                float* __restrict__ out, int Q) {
    int q = blockIdx.x * blockDim.x + threadIdx.x;
    if (q >= Q) return;
    ull key = packed[q];
    unsigned m = ~((unsigned)(key & 0xFFFFFFFFu));
    float conf = funmap((unsigned)(key >> 32)) * rq[q];   // apply row norm here
    out[q] = (float)memvals[m];
    out[Q + q] = conf;
}

__global__ void finish_upd(const unsigned* __restrict__ maxsim,
                           const ull* __restrict__ minall,
                           const ull* __restrict__ minsame,
                           const float* __restrict__ ru,
                           int* __restrict__ wtgt, int Bn) {
    __shared__ int tg[256];
    __shared__ unsigned char du[256];
    int b = threadIdx.x;
    int t = -1; bool d = false;
    if (b < Bn) {
        d = funmap(maxsim[b]) * ru[b] < 0.8f;             // apply row norm here
        ull ks = minsame[b];
        ull ka = minall[b];
        t = (ks != ~0ULL) ? (int)(ks & 0xFFFFFFFFu) : (int)(ka & 0xFFFFFFFFu);
        tg[b] = t; du[b] = d ? 1 : 0;
    }
    __syncthreads();
    if (b < Bn) {
        bool win = d;
        if (win)
            for (int b2 = b + 1; b2 < Bn; ++b2)
                if (du[b2] && tg[b2] == t) { win = false; break; }
        wtgt[b] = win ? t : -1;
    }
}

__global__ void copy_keys(const f4v* __restrict__ src, f4v* __restrict__ dst, long n4) {
    long i = blockIdx.x * (long)blockDim.x + threadIdx.x;
    long stride = (long)gridDim.x * blockDim.x;
    for (; i < n4; i += stride) nt_store_f4(nt_load_f4(&src[i]), &dst[i]);
}

__global__ void copy_vals(const int* __restrict__ src, float* __restrict__ dst, int n) {
    int i = blockIdx.x * blockDim.x + threadIdx.x;
    if (i < n) dst[i] = (float)src[i];
}

__global__ void scatter_kernel(const int* __restrict__ wtgt, const float4* __restrict__ upd4,
                               const int* __restrict__ lbl, float4* __restrict__ keys4,
                               float* __restrict__ vals) {
    int b = blockIdx.x;
    int t = wtgt[b];
    if (t < 0) return;
    int l = threadIdx.x; // 64 threads x float4 = 256 floats
    keys4[(long)t * 64 + l] = upd4[(long)b * 64 + l];
    if (l == 0) vals[t] = (float)lbl[b];
}

// ---------- launch ----------

extern "C" void kernel_launch(void* const* d_in, const int* in_sizes, int n_in,
                              void* d_out, int out_size, void* d_ws, size_t ws_size,
                              hipStream_t stream) {
    const float* qf = (const float*)d_in[0];
    const float* mk = (const float*)d_in[1];
    const int*   mv = (const int*)d_in[2];
    const float* uf = (const float*)d_in[3];
    const int*   ul = (const int*)d_in[4];

    const int D = 256;
    const int Q = in_sizes[0] / D;   // 2048
    const int M = in_sizes[2];       // 100000
    const int Bn = in_sizes[3] / D;  // 128

    float* out = (float*)d_out;
    float* out_keys = out + 2 * (long)Q;
    float* out_vals = out_keys + (long)M * D;

    // B fragment arrays live in the out_keys region (exact fit). copy_keys
    // overwrites them afterwards.
    _Float16* Bh = (_Float16*)out_keys;
    _Float16* Bl = Bh + (size_t)M * D;

    // Reduction scratch + norms live in the out_vals region (cacheable d_out,
    // unlike d_ws whose reads bypass L2). copy_vals overwrites at the end.
    char* ov = (char*)out_vals;
    ull* packed      = (ull*)(ov);                         // 16 KB
    ull* minall      = (ull*)(ov + 16384);                 // 1 KB
    ull* minsame     = (ull*)(ov + 17408);                 // 1 KB
    unsigned* maxsim = (unsigned*)(ov + 18432);            // 0.5 KB
    float* rq        = (float*)(ov + 18944);               // 8 KB
    float* ru        = (float*)(ov + 27136);               // 0.5 KB

    // d_ws only holds atomic-free, rarely-touched data.
    int* wtgt = (int*)d_ws;

    const int Mtiles = (M + 15) / 16;          // 6250
    const int msets = (Mtiles + 7) / 8;        // 782
    const int grid_g = msets * 2;              // 1564 (half q-sweep each)

    int initN = (Q > Bn ? Q : Bn);
    init_kernel<<<(initN + 255) / 256, 256, 0, stream>>>(packed, maxsim, minall, minsame, Q, Bn);

    norms_kernel<<<(Q + 3) / 4, 256, 0, stream>>>(qf, rq, Q);
    norms_kernel<<<(Bn + 3) / 4, 256, 0, stream>>>(uf, ru, Bn);

    prep_b<<<Mtiles, 256, 0, stream>>>(mk, Bh, Bl, M);

    retrieve_fused<<<grid_g, 512, 0, stream>>>(
        qf, uf, (const half8*)Bh, (const half8*)Bl, mv, ul,
        packed, maxsim, minall, minsame, M, Mtiles, Q, Bn);

    finish_retrieve<<<(Q + 255) / 256, 256, 0, stream>>>(packed, mv, rq, out, Q);
    finish_upd<<<1, Bn, 0, stream>>>(maxsim, minall, minsame, ru, wtgt, Bn);

    // Overwrite scratch regions with the real outputs (stream-ordered).
    copy_keys<<<2048, 256, 0, stream>>>((const f4v*)mk, (f4v*)out_keys, (long)M * (D / 4));
    copy_vals<<<(M + 255) / 256, 256, 0, stream>>>(mv, out_vals, M);
    scatter_kernel<<<Bn, 64, 0, stream>>>(wtgt, (const float4*)uf, ul, (float4*)out_keys, out_vals);
}